// Round 4
// baseline (77.151 us; speedup 1.0000x reference)
//
#include <hip/hip_runtime.h>

// LinearCondensed: out[b,o] = sum_k w[o,k] * x[b, idx[o,k]] + bias[o]
// B=2048, IN_F=4096, OUT_F=4096, K=32, f32 in/out (idx int32).
//
// v4: same bf16 8-row-packed gather as v3 (one ds_read_b128 = col c of 8
// batch rows), but SINGLE 64KB LDS buffer -> 2 blocks/CU (16 waves/CU).
// Next tile is double-buffered in REGISTERS (T14: issue loads before the
// gather, pack+ds_write after it, between two barriers). Cross-block overlap
// hides the barrier drain that capped v3 at 19% occupancy.

constexpr int IN_F  = 4096;
constexpr int OUT_F = 4096;
constexpr int K     = 32;
constexpr int BT    = 8;                     // batch rows per iteration
constexpr int THREADS = 512;                 // 1 output column per thread
constexpr int ROWS_PER_BLOCK = 32;
constexpr int ITERS = ROWS_PER_BLOCK / BT;   // 4
constexpr int CPT = IN_F / THREADS;          // 8 columns staged per thread

__device__ __forceinline__ unsigned pack_bf16(float lo, float hi) {
    return (__float_as_uint(hi) & 0xffff0000u) | (__float_as_uint(lo) >> 16);
}
__device__ __forceinline__ float bf_lo(unsigned u) { return __uint_as_float(u << 16); }
__device__ __forceinline__ float bf_hi(unsigned u) { return __uint_as_float(u & 0xffff0000u); }

__global__ __launch_bounds__(THREADS, 4)
void lc_kernel(const float* __restrict__ x,
               const float* __restrict__ w,
               const float* __restrict__ bias,
               const int* __restrict__ idx,
               float* __restrict__ out,
               int bchunks) {
    // xs[c] = {rows 0..7 of col c, 4x packed bf16 pairs} -- 64 KiB, 2 blocks/CU
    __shared__ int4 xs[IN_F];
    const int tid = threadIdx.x;
    // bid = ochunk*bchunks + bchunk; bchunks=64 -> bid%8 = bchunk%8, so the
    // 8 blocks sharing one x b-chunk land on the same XCD -> x re-reads = L2 hits
    const int ochunk = blockIdx.x / bchunks;
    const int bchunk = blockIdx.x % bchunks;
    const int o = ochunk * THREADS + tid;

    // idx (as byte offsets into the 64KB buffer) + weights in registers, once.
    int   ao[K];
    float wr[K];
    const int4*   ip = reinterpret_cast<const int4*>(idx + (size_t)o * K);
    const float4* wp = reinterpret_cast<const float4*>(w + (size_t)o * K);
#pragma unroll
    for (int kk = 0; kk < K / 4; ++kk) {
        int4   i4 = ip[kk];
        float4 w4 = wp[kk];
        ao[4*kk+0] = i4.x << 4;  ao[4*kk+1] = i4.y << 4;
        ao[4*kk+2] = i4.z << 4;  ao[4*kk+3] = i4.w << 4;
        wr[4*kk+0] = w4.x;  wr[4*kk+1] = w4.y;
        wr[4*kk+2] = w4.z;  wr[4*kk+3] = w4.w;
    }
    const float bv = bias[o];
    const int b0 = bchunk * ROWS_PER_BLOCK;

    float pf[BT * CPT];                       // next tile, register-resident

    // ---- prologue: stage tile 0 (latency exposed once per block) ----
    {
        const float* xr = x + (size_t)b0 * IN_F;
#pragma unroll
        for (int j = 0; j < CPT; ++j)
#pragma unroll
            for (int r = 0; r < BT; ++r)
                pf[j * BT + r] = xr[(size_t)r * IN_F + tid + j * THREADS];
#pragma unroll
        for (int j = 0; j < CPT; ++j) {
            int4 pk;
            pk.x = (int)pack_bf16(pf[j*BT+0], pf[j*BT+1]);
            pk.y = (int)pack_bf16(pf[j*BT+2], pf[j*BT+3]);
            pk.z = (int)pack_bf16(pf[j*BT+4], pf[j*BT+5]);
            pk.w = (int)pack_bf16(pf[j*BT+6], pf[j*BT+7]);
            xs[tid + j * THREADS] = pk;
        }
    }
    __syncthreads();

    const char* xb = reinterpret_cast<const char*>(&xs[0]);

#pragma unroll
    for (int it = 0; it < ITERS; ++it) {
        // T14 issue-early: next tile's global loads go in flight now; the
        // vmcnt wait lands after the gather loop (~3000 cycles later).
        if (it + 1 < ITERS) {
            const float* xr = x + (size_t)(b0 + (it + 1) * BT) * IN_F;
#pragma unroll
            for (int j = 0; j < CPT; ++j)
#pragma unroll
                for (int r = 0; r < BT; ++r)
                    pf[j * BT + r] = xr[(size_t)r * IN_F + tid + j * THREADS];
        }

        // ---- gather + FMA: 32 ds_read_b128, each feeds 8 row-accumulators ----
        float acc[BT];
#pragma unroll
        for (int r = 0; r < BT; ++r) acc[r] = bv;
#pragma unroll
        for (int k = 0; k < K; ++k) {
            int4 v = *reinterpret_cast<const int4*>(xb + ao[k]);
            const float wk = wr[k];
            acc[0] += wk * bf_lo((unsigned)v.x);
            acc[1] += wk * bf_hi((unsigned)v.x);
            acc[2] += wk * bf_lo((unsigned)v.y);
            acc[3] += wk * bf_hi((unsigned)v.y);
            acc[4] += wk * bf_lo((unsigned)v.z);
            acc[5] += wk * bf_hi((unsigned)v.z);
            acc[6] += wk * bf_lo((unsigned)v.w);
            acc[7] += wk * bf_hi((unsigned)v.w);
        }

        // coalesced stores: 8 rows x 2KB per block-row
        float* op = out + (size_t)(b0 + it * BT) * OUT_F + o;
#pragma unroll
        for (int r = 0; r < BT; ++r) op[(size_t)r * OUT_F] = acc[r];

        // T14 write-late: reuse the single buffer between two barriers.
        // While this block sits here, the co-resident block gathers.
        if (it + 1 < ITERS) {
            __syncthreads();                  // all gathers on xs done
#pragma unroll
            for (int j = 0; j < CPT; ++j) {
                int4 pk;
                pk.x = (int)pack_bf16(pf[j*BT+0], pf[j*BT+1]);
                pk.y = (int)pack_bf16(pf[j*BT+2], pf[j*BT+3]);
                pk.z = (int)pack_bf16(pf[j*BT+4], pf[j*BT+5]);
                pk.w = (int)pack_bf16(pf[j*BT+6], pf[j*BT+7]);
                xs[tid + j * THREADS] = pk;
            }
            __syncthreads();                  // new tile visible
        }
    }
}

extern "C" void kernel_launch(void* const* d_in, const int* in_sizes, int n_in,
                              void* d_out, int out_size, void* d_ws, size_t ws_size,
                              hipStream_t stream) {
    const float* x    = (const float*)d_in[0];
    const float* w    = (const float*)d_in[1];
    const float* bias = (const float*)d_in[2];
    const int*   idx  = (const int*)d_in[3];
    float* out = (float*)d_out;

    const int Bv = in_sizes[0] / IN_F;           // 2048
    const int bchunks = Bv / ROWS_PER_BLOCK;     // 64
    const int ochunks = (in_sizes[1] / K) / THREADS;  // 8
    lc_kernel<<<dim3(ochunks * bchunks), dim3(THREADS), 0, stream>>>(
        x, w, bias, idx, out, bchunks);
}

// Round 6
// 41.299 us; speedup vs baseline: 1.8681x; 1.8681x over previous
//
#include <hip/hip_runtime.h>

// LinearCondensed: out[b,o] = sum_k w[o,k] * x[b, idx[o,k]] + bias[o]
// B=2048, IN_F=4096, OUT_F=4096, K=32, f32 in/out (idx int32).
//
// v5b: x staged in LDS as f16, 8 rows packed per column (int4 per col) ->
// one ds_read_b128 gathers col c of 8 batch rows. Single 64KB LDS buffer
// (2 blocks/CU); next tile double-buffered in REGISTERS (T14 issue-early /
// write-late between two barriers). f16 via v_cvt_pkrtz pack; unpack fused
// into v_fma_mix_f32 (compiler-matched from (float)half * f32 + f32).
// NO min-waves launch bound: v4's __launch_bounds__(512,4) spilled pf[] to
// scratch (FETCH 36->95MB, WRITE 32->148MB) and regressed 2x.

constexpr int IN_F  = 4096;
constexpr int OUT_F = 4096;
constexpr int K     = 32;
constexpr int BT    = 8;                     // batch rows per iteration
constexpr int THREADS = 512;                 // 1 output column per thread
constexpr int ROWS_PER_BLOCK = 32;
constexpr int ITERS = ROWS_PER_BLOCK / BT;   // 4
constexpr int CPT = IN_F / THREADS;          // 8 columns staged per thread

typedef __fp16 h2_t __attribute__((ext_vector_type(2)));

__device__ __forceinline__ int pack_f16(float lo, float hi) {
    union { h2_t h; int i; } cv;
    cv.h = __builtin_amdgcn_cvt_pkrtz(lo, hi);   // v_cvt_pkrtz_f16_f32
    return cv.i;
}
__device__ __forceinline__ float h_lo(int u) {
    union { int i; h2_t h; } cv; cv.i = u; return (float)cv.h[0];
}
__device__ __forceinline__ float h_hi(int u) {
    union { int i; h2_t h; } cv; cv.i = u; return (float)cv.h[1];
}

__global__ __launch_bounds__(THREADS)
void lc_kernel(const float* __restrict__ x,
               const float* __restrict__ w,
               const float* __restrict__ bias,
               const int* __restrict__ idx,
               float* __restrict__ out,
               int bchunks) {
    // xs[c] = {rows 0..7 of col c, 4x packed f16 pairs} -- 64 KiB, 2 blocks/CU
    __shared__ int4 xs[IN_F];
    const int tid = threadIdx.x;
    // bid = ochunk*bchunks + bchunk; bchunks=64 -> bid%8 = bchunk%8, so the
    // 8 blocks sharing one x b-chunk land on the same XCD -> x re-reads L2-hit
    const int ochunk = blockIdx.x / bchunks;
    const int bchunk = blockIdx.x % bchunks;
    const int o = ochunk * THREADS + tid;

    // idx (as byte offsets into the 64KB buffer) + weights in registers, once.
    int   ao[K];
    float wr[K];
    const int4*   ip = reinterpret_cast<const int4*>(idx + (size_t)o * K);
    const float4* wp = reinterpret_cast<const float4*>(w + (size_t)o * K);
#pragma unroll
    for (int kk = 0; kk < K / 4; ++kk) {
        int4   i4 = ip[kk];
        float4 w4 = wp[kk];
        ao[4*kk+0] = i4.x << 4;  ao[4*kk+1] = i4.y << 4;
        ao[4*kk+2] = i4.z << 4;  ao[4*kk+3] = i4.w << 4;
        wr[4*kk+0] = w4.x;  wr[4*kk+1] = w4.y;
        wr[4*kk+2] = w4.z;  wr[4*kk+3] = w4.w;
    }
    const float bv = bias[o];
    const int b0 = bchunk * ROWS_PER_BLOCK;

    float pf[BT * CPT];                       // next tile, register-resident

    // ---- prologue: stage tile 0 (latency exposed once per block) ----
    {
        const float* xr = x + (size_t)b0 * IN_F;
#pragma unroll
        for (int j = 0; j < CPT; ++j)
#pragma unroll
            for (int r = 0; r < BT; ++r)
                pf[j * BT + r] = xr[(size_t)r * IN_F + tid + j * THREADS];
#pragma unroll
        for (int j = 0; j < CPT; ++j) {
            int4 pk;
            pk.x = pack_f16(pf[j*BT+0], pf[j*BT+1]);
            pk.y = pack_f16(pf[j*BT+2], pf[j*BT+3]);
            pk.z = pack_f16(pf[j*BT+4], pf[j*BT+5]);
            pk.w = pack_f16(pf[j*BT+6], pf[j*BT+7]);
            xs[tid + j * THREADS] = pk;
        }
    }
    __syncthreads();

    const char* xb = reinterpret_cast<const char*>(&xs[0]);

#pragma unroll
    for (int it = 0; it < ITERS; ++it) {
        // T14 issue-early: next tile's global loads go in flight now; the
        // vmcnt wait lands after the gather loop (~2000+ cycles later).
        if (it + 1 < ITERS) {
            const float* xr = x + (size_t)(b0 + (it + 1) * BT) * IN_F;
#pragma unroll
            for (int j = 0; j < CPT; ++j)
#pragma unroll
                for (int r = 0; r < BT; ++r)
                    pf[j * BT + r] = xr[(size_t)r * IN_F + tid + j * THREADS];
        }

        // ---- gather + FMA: 32 ds_read_b128, 256 v_fma_mix_f32 ----
        float acc[BT];
#pragma unroll
        for (int r = 0; r < BT; ++r) acc[r] = bv;
#pragma unroll
        for (int k = 0; k < K; ++k) {
            int4 v = *reinterpret_cast<const int4*>(xb + ao[k]);
            const float wk = wr[k];
            acc[0] += wk * h_lo(v.x);
            acc[1] += wk * h_hi(v.x);
            acc[2] += wk * h_lo(v.y);
            acc[3] += wk * h_hi(v.y);
            acc[4] += wk * h_lo(v.z);
            acc[5] += wk * h_hi(v.z);
            acc[6] += wk * h_lo(v.w);
            acc[7] += wk * h_hi(v.w);
        }

        // coalesced stores: 8 rows x 2KB per block-row
        float* op = out + (size_t)(b0 + it * BT) * OUT_F + o;
#pragma unroll
        for (int r = 0; r < BT; ++r) op[(size_t)r * OUT_F] = acc[r];

        // T14 write-late: reuse the single buffer between two barriers.
        // While this block sits here, the co-resident block gathers.
        if (it + 1 < ITERS) {
            __syncthreads();                  // all gathers on xs done
#pragma unroll
            for (int j = 0; j < CPT; ++j) {
                int4 pk;
                pk.x = pack_f16(pf[j*BT+0], pf[j*BT+1]);
                pk.y = pack_f16(pf[j*BT+2], pf[j*BT+3]);
                pk.z = pack_f16(pf[j*BT+4], pf[j*BT+5]);
                pk.w = pack_f16(pf[j*BT+6], pf[j*BT+7]);
                xs[tid + j * THREADS] = pk;
            }
            __syncthreads();                  // new tile visible
        }
    }
}

extern "C" void kernel_launch(void* const* d_in, const int* in_sizes, int n_in,
                              void* d_out, int out_size, void* d_ws, size_t ws_size,
                              hipStream_t stream) {
    const float* x    = (const float*)d_in[0];
    const float* w    = (const float*)d_in[1];
    const float* bias = (const float*)d_in[2];
    const int*   idx  = (const int*)d_in[3];
    float* out = (float*)d_out;

    const int Bv = in_sizes[0] / IN_F;           // 2048
    const int bchunks = Bv / ROWS_PER_BLOCK;     // 64
    const int ochunks = (in_sizes[1] / K) / THREADS;  // 8
    lc_kernel<<<dim3(ochunks * bchunks), dim3(THREADS), 0, stream>>>(
        x, w, bias, idx, out, bchunks);
}